// Round 3
// baseline (44.894 us; speedup 1.0000x reference)
//
#include <hip/hip_runtime.h>
#include <math.h>

// Problem constants (from reference setup_inputs)
#define B_TOT 32
#define C_TOT 128
#define G_TOT 4096
#define BODY  4
#define M_TOT 5

// Tiling
#define B_PER 4            // batch rows per block, packed as fp16x4 per g in LDS
#define CQ    8            // c-loop split across 8 adjacent lanes
#define GPB   64           // g outputs per block
#define THREADS (GPB*CQ)   // 512
#define C_PER (C_TOT/CQ)   // 16 c-iterations per thread

typedef float    f32x2 __attribute__((ext_vector_type(2)));
typedef _Float16 h16x4 __attribute__((ext_vector_type(4)));

__device__ __forceinline__ void pk_fma(f32x2& d, f32x2 a, f32x2 b) {
    asm("v_pk_fma_f32 %0, %1, %2, %0" : "+v"(d) : "v"(a), "v"(b));
}

// ---- softmax over W rows (5 x 128), transposed+padded output wt[c][8] ----
__global__ void softmax_w_kernel(const float* __restrict__ W, float* __restrict__ Wt) {
    const int lane = threadIdx.x; // 64 threads
    for (int m = 0; m < M_TOT; ++m) {
        float a = W[m * C_TOT + lane];
        float b = W[m * C_TOT + lane + 64];
        float mx = fmaxf(a, b);
        #pragma unroll
        for (int off = 32; off; off >>= 1) mx = fmaxf(mx, __shfl_xor(mx, off));
        float ea = expf(a - mx), eb = expf(b - mx);
        float s = ea + eb;
        #pragma unroll
        for (int off = 32; off; off >>= 1) s += __shfl_xor(s, off);
        Wt[lane * 8 + m]        = ea / s;
        Wt[(lane + 64) * 8 + m] = eb / s;
    }
}

// ---- one t-step: v_out = softor(v_in, softor_m(h)) ----
__global__ __launch_bounds__(THREADS, 4) void step_kernel(
    const float* __restrict__ v_in,   // (B, G) fp32
    const int*   __restrict__ X,      // (C, G, 4) int32
    const int*   __restrict__ fact,   // (C, G) int32 (0/1)
    const float* __restrict__ Wt,     // (128, 8) softmaxed, transposed, padded
    float*       __restrict__ v_out)  // (B, G) fp32
{
    __shared__ h16x4 lvh[G_TOT + 8];   // ~32 KB: v[b0..b0+3][g] as fp16x4; sentinel at [G_TOT]=0
    __shared__ float lwt[C_TOT * 8];   // 4 KB

    const int tid = threadIdx.x;
    const int b0  = blockIdx.y * B_PER;
    const int gt  = blockIdx.x * GPB;

    // stage Wt
    for (int i = tid; i < C_TOT * 8; i += THREADS) lwt[i] = Wt[i];

    // stage v transposed + converted to fp16 (coalesced global reads per row)
    for (int g = tid; g < G_TOT; g += THREADS) {
        float a = v_in[(size_t)(b0 + 0) * G_TOT + g];
        float b = v_in[(size_t)(b0 + 1) * G_TOT + g];
        float c = v_in[(size_t)(b0 + 2) * G_TOT + g];
        float d = v_in[(size_t)(b0 + 3) * G_TOT + g];
        h16x4 t = { (_Float16)a, (_Float16)b, (_Float16)c, (_Float16)d };
        lvh[g] = t;
    }
    if (tid < 8) lvh[G_TOT + tid] = (h16x4){ (_Float16)0.f, (_Float16)0.f,
                                             (_Float16)0.f, (_Float16)0.f };
    __syncthreads();

    const int cq = tid & (CQ - 1);
    const int gl = tid >> 3;
    const int g  = gt + gl;

    f32x2 hlo[M_TOT], hhi[M_TOT];
    #pragma unroll
    for (int m = 0; m < M_TOT; ++m) { hlo[m] = (f32x2){0.f, 0.f}; hhi[m] = (f32x2){0.f, 0.f}; }

    #pragma unroll 4
    for (int ci = 0; ci < C_PER; ++ci) {
        const int c = ci * CQ + cq;                 // interleaved c-partition
        const int4 xi = ((const int4*)X)[(size_t)c * G_TOT + g];
        const int  fm = fact[(size_t)c * G_TOT + g];
        const float* wp = &lwt[c * 8];

        // fact lanes gather the shared sentinel (LDS broadcast, conflict-free)
        const int i0 = fm ? G_TOT : xi.x;
        const int i1 = fm ? G_TOT : xi.y;
        const int i2 = fm ? G_TOT : xi.z;
        const int i3 = fm ? G_TOT : xi.w;

        const h16x4 va = lvh[i0];
        const h16x4 vb = lvh[i1];
        const h16x4 vc = lvh[i2];
        const h16x4 vd = lvh[i3];

        h16x4 p = va * vb;                          // v_pk_mul_f16
        p = p * vc;
        p = p * vd;

        const float ff = fm ? 1.0f : 0.0f;          // clause value for facts is 1
        const f32x2 plo = { (float)p.x + ff, (float)p.y + ff };
        const f32x2 phi = { (float)p.z + ff, (float)p.w + ff };

        #pragma unroll
        for (int m = 0; m < M_TOT; ++m) {
            const float w = wp[m];
            const f32x2 ws = (f32x2){w, w};
            pk_fma(hlo[m], plo, ws);
            pk_fma(hhi[m], phi, ws);
        }
    }

    // butterfly reduce over the 8 cq lanes; all lanes end with full sums
    float hs[M_TOT][B_PER];
    #pragma unroll
    for (int m = 0; m < M_TOT; ++m) {
        hs[m][0] = hlo[m].x; hs[m][1] = hlo[m].y;
        hs[m][2] = hhi[m].x; hs[m][3] = hhi[m].y;
    }
    #pragma unroll
    for (int m = 0; m < M_TOT; ++m)
        #pragma unroll
        for (int b = 0; b < B_PER; ++b) {
            float s = hs[m][b];
            s += __shfl_xor(s, 1);
            s += __shfl_xor(s, 2);
            s += __shfl_xor(s, 4);
            hs[m][b] = s;
        }

    // epilogue: 4 of the 8 cq lanes each write one b (v_old re-read in fp32)
    if (cq < B_PER) {
        const int b = cq;
        float om = 1.0f;
        #pragma unroll
        for (int m = 0; m < M_TOT; ++m) om *= (1.0f - hs[m][b]);
        float r = 1.0f - om;
        r = fminf(fmaxf(r, 0.0f), 1.0f);
        const float vold = v_in[(size_t)(b0 + b) * G_TOT + g];
        float vn = 1.0f - (1.0f - vold) * (1.0f - r);
        vn = fminf(fmaxf(vn, 0.0f), 1.0f);
        v_out[(size_t)(b0 + b) * G_TOT + g] = vn;
    }
}

extern "C" void kernel_launch(void* const* d_in, const int* in_sizes, int n_in,
                              void* d_out, int out_size, void* d_ws, size_t ws_size,
                              hipStream_t stream) {
    const float* v0   = (const float*)d_in[0];
    const int*   X    = (const int*)  d_in[1];   // int64 in ref -> int32 on device
    const int*   fact = (const int*)  d_in[2];   // bool in ref  -> int32 on device
    const float* W    = (const float*)d_in[3];
    float*       out  = (float*)d_out;

    float* wt = (float*)d_ws;                // 1024 floats (4 KB), wt[c][8]
    float* v1 = (float*)d_ws + 1024;         // intermediate v (512 KB)

    softmax_w_kernel<<<1, 64, 0, stream>>>(W, wt);

    dim3 grid(G_TOT / GPB, B_TOT / B_PER);   // (64, 8) = 512 blocks
    step_kernel<<<grid, THREADS, 0, stream>>>(v0, X, fact, wt, v1);
    step_kernel<<<grid, THREADS, 0, stream>>>(v1, X, fact, wt, out);
}